// Round 7
// baseline (244.307 us; speedup 1.0000x reference)
//
#include <hip/hip_runtime.h>
#include <hip/hip_bf16.h>

#define N_TOK 16384
#define DIM   2048
#define NEXP  64
#define BM    32                 // tokens per block
#define NBLK  (N_TOK / BM)       // 512 blocks = 2 per CU
#define KSPL  2                  // K-split across wave pairs
#define KW    (DIM / KSPL)       // 1024 k per wave
#define NS    (KW / 32)          // 32 MFMA k-steps per wave

// d_out layout (all float32), reference tuple order:
// (l_aux, indices1_s[N], capacity, locations1_s[N], gates1_s[N], E)
#define OFF_LAUX  0
#define OFF_IDX   1
#define OFF_CAP   (1 + N_TOK)
#define OFF_LOC   (2 + N_TOK)
#define OFF_GATES (2 + 2 * N_TOK)
#define OFF_E     (2 + 3 * N_TOK)

typedef __attribute__((ext_vector_type(8))) short short8;   // 8 bf16 = 4 VGPR
typedef __attribute__((ext_vector_type(4))) float f32x4;

__device__ __forceinline__ short f2bf(float x) {
    __hip_bfloat16 b = __float2bfloat16(x);          // RNE
    return __builtin_bit_cast(short, b);
}
__device__ __forceinline__ float bf2f(short s) {
    __hip_bfloat16 b = __builtin_bit_cast(__hip_bfloat16, s);
    return __bfloat162float(b);
}

// ---------------------------------------------------------------------------
// K0: split wg (fp32 [64][2048]) into 3 bf16 arrays in mfma_f32_16x16x32_bf16
// B-fragment order: idx = (s*4+g)*64 + lane; expert = 16g + (lane&15),
// k = 32s + (lane>>4)*8 + j.  w = w1+w2+w3, exact fp32 residuals.
// (Layout HW-proven in r5: argmax matched exactly.)
// ---------------------------------------------------------------------------
__global__ __launch_bounds__(256)
void prep_w_kernel(const float* __restrict__ wg,
                   short8* __restrict__ w1a,
                   short8* __restrict__ w2a,
                   short8* __restrict__ w3a)
{
    const int id = blockIdx.x * 256 + threadIdx.x;   // 0..16383
    const int s = id >> 8;
    const int g = (id >> 6) & 3;
    const int l = id & 63;
    const int e  = 16 * g + (l & 15);
    const int k0 = 32 * s + (l >> 4) * 8;
    const float4* p = reinterpret_cast<const float4*>(wg + (size_t)e * DIM + k0);
    float4 v0 = p[0], v1 = p[1];
    float f[8] = {v0.x, v0.y, v0.z, v0.w, v1.x, v1.y, v1.z, v1.w};
    short8 b1, b2, b3;
    #pragma unroll
    for (int j = 0; j < 8; ++j) {
        b1[j] = f2bf(f[j]);
        float r = f[j] - bf2f(b1[j]);
        b2[j] = f2bf(r);
        float r2 = r - bf2f(b2[j]);
        b3[j] = f2bf(r2);
    }
    w1a[id] = b1; w2a[id] = b2; w3a[id] = b3;
}

// ---------------------------------------------------------------------------
// K1: logits via 6 bf16 MFMAs per 32-k step (fp32-exact 3-way split).
// r6 restructure per r5 counters (latency-bound, all pipes ~90% idle):
//  - K-split x2: wave w -> token-group tg=w&1 (16 tokens), k-half kh=w>>1.
//    512 blocks x 4 waves = 8 waves/CU = 2/SIMD; LDS partial reduce.
//  - register DOUBLE-BUFFER for both A (fp32 global) and B (bf16 frags):
//    per step s: issue b(s+1) -> bO, consume/split A(s) from aC, issue
//    A(s+2) into aC (freed), MFMA with bC. In-order vmcnt then gives B one
//    full iteration of slack and A two -> no per-step latency exposure
//    (r5's bug: B waits drained the A prefetch every step).
//  - manual 2-unroll so all buffer indices are static (no scratch).
// ---------------------------------------------------------------------------
__global__ __launch_bounds__(256)
void gate_mfma_kernel(const float* __restrict__ inp,
                      const short8* __restrict__ w1a,
                      const short8* __restrict__ w2a,
                      const short8* __restrict__ w3a,
                      float* __restrict__ out,
                      float* __restrict__ me_p,
                      int* __restrict__ hist,
                      int* __restrict__ idx_g,
                      int* __restrict__ rank_g)
{
    __shared__ float lgp[KSPL][BM][NEXP + 1];   // 16.6 KB partials / P-values
    __shared__ float pme[4][NEXP];
    __shared__ int   am_s[BM];

    const int tid  = threadIdx.x;
    const int w    = tid >> 6;
    const int lane = tid & 63;
    const int tg   = w & 1;      // token group
    const int kh   = w >> 1;     // k half
    const int blk  = blockIdx.x;
    const int row0 = blk * BM;

    const float* aptr = inp + (size_t)(row0 + 16 * tg + (lane & 15)) * DIM
                        + kh * KW + ((lane >> 4) * 8);
    const int bbase = (NS * kh) * 256 + lane;    // short8 units

    f32x4 acc[4] = {{0.f,0.f,0.f,0.f},{0.f,0.f,0.f,0.f},
                    {0.f,0.f,0.f,0.f},{0.f,0.f,0.f,0.f}};

    float4 aA[2], aB[2];
    short8 bA[12], bB[12];

    auto loadA = [&](float4 (&buf)[2], int s) {
        buf[0] = *reinterpret_cast<const float4*>(aptr + 32 * s);
        buf[1] = *reinterpret_cast<const float4*>(aptr + 32 * s + 4);
    };
    auto loadB = [&](short8 (&buf)[12], int s) {
        const int o = bbase + s * 256;
        #pragma unroll
        for (int g = 0; g < 4; ++g) {
            buf[3 * g + 0] = w1a[o + g * 64];
            buf[3 * g + 1] = w2a[o + g * 64];
            buf[3 * g + 2] = w3a[o + g * 64];
        }
    };
    auto step = [&](int s, float4 (&aC)[2], short8 (&bC)[12], short8 (&bO)[12]) {
        if (s + 1 < NS) loadB(bO, s + 1);          // B for next step (1-iter slack)
        const float4 v0 = aC[0], v1 = aC[1];       // waits: A loaded 2 iters ago
        float f[8] = {v0.x, v0.y, v0.z, v0.w, v1.x, v1.y, v1.z, v1.w};
        short8 a1, a2, a3;
        #pragma unroll
        for (int j = 0; j < 8; ++j) {
            a1[j] = f2bf(f[j]);
            float r = f[j] - bf2f(a1[j]);
            a2[j] = f2bf(r);
            float r2 = r - bf2f(a2[j]);
            a3[j] = f2bf(r2);
        }
        if (s + 2 < NS) loadA(aC, s + 2);          // refill freed buffer (2-iter slack)
        #pragma unroll
        for (int g = 0; g < 4; ++g) {
            const short8 b1 = bC[3 * g + 0];
            const short8 b2 = bC[3 * g + 1];
            const short8 b3 = bC[3 * g + 2];
            acc[g] = __builtin_amdgcn_mfma_f32_16x16x32_bf16(a1, b3, acc[g], 0, 0, 0);
            acc[g] = __builtin_amdgcn_mfma_f32_16x16x32_bf16(a2, b2, acc[g], 0, 0, 0);
            acc[g] = __builtin_amdgcn_mfma_f32_16x16x32_bf16(a3, b1, acc[g], 0, 0, 0);
            acc[g] = __builtin_amdgcn_mfma_f32_16x16x32_bf16(a1, b2, acc[g], 0, 0, 0);
            acc[g] = __builtin_amdgcn_mfma_f32_16x16x32_bf16(a2, b1, acc[g], 0, 0, 0);
            acc[g] = __builtin_amdgcn_mfma_f32_16x16x32_bf16(a1, b1, acc[g], 0, 0, 0);
        }
    };

    loadA(aA, 0); loadA(aB, 1); loadB(bA, 0);
    for (int s = 0; s < NS; s += 2) {
        step(s,     aA, bA, bB);
        step(s + 1, aB, bB, bA);
    }

    // D layout (HW-proven r5): col = lane&15 (expert), row = (lane>>4)*4 + r
    #pragma unroll
    for (int g = 0; g < 4; ++g)
        #pragma unroll
        for (int r = 0; r < 4; ++r)
            lgp[kh][16 * tg + ((lane >> 4) << 2) + r][16 * g + (lane & 15)] = acc[g][r];
    __syncthreads();

    // reduce K-halves + per-token softmax/argmax: 8 threads per token
    const int tok = tid >> 3;    // 0..31
    const int q   = tid & 7;     // experts 8q..8q+7
    float v[8];
    #pragma unroll
    for (int i = 0; i < 8; ++i)
        v[i] = lgp[0][tok][8 * q + i] + lgp[1][tok][8 * q + i];
    float mx = v[0]; int ai = 8 * q;
    #pragma unroll
    for (int i = 1; i < 8; ++i)
        if (v[i] > mx) { mx = v[i]; ai = 8 * q + i; }     // strict > = first max
    #pragma unroll
    for (int d = 1; d < 8; d <<= 1) {
        float om = __shfl_xor(mx, d);
        int   oi = __shfl_xor(ai, d);
        if (om > mx || (om == mx && oi < ai)) { mx = om; ai = oi; }
    }
    float p[8], sum = 0.f;
    #pragma unroll
    for (int i = 0; i < 8; ++i) { p[i] = expf(v[i] - mx); sum += p[i]; }
    #pragma unroll
    for (int d = 1; d < 8; d <<= 1) sum += __shfl_xor(sum, d);
    const float inv = 1.0f / sum;                          // gate at argmax
    #pragma unroll
    for (int i = 0; i < 8; ++i) lgp[0][tok][8 * q + i] = p[i] * inv;
    if (q == 0) {
        am_s[tok] = ai;
        idx_g[row0 + tok] = ai;
        out[OFF_IDX + row0 + tok]   = (float)ai;
        out[OFF_GATES + row0 + tok] = inv;
    }
    __syncthreads();

    // me[e] partials: thread (g2=tid>>6, e=tid&63) sums 8 token rows
    {
        const int e = tid & 63, g2 = tid >> 6;
        float a = 0.f;
        #pragma unroll
        for (int t = 0; t < 8; ++t) a += lgp[0][8 * g2 + t][e];
        pme[g2][e] = a;
    }
    __syncthreads();
    if (tid < NEXP)
        me_p[blk * NEXP + tid] = pme[0][tid] + pme[1][tid] + pme[2][tid] + pme[3][tid];

    // ranks + histogram: lanes 0..31 of wave 0 (32 tokens)
    if (tid < BM) {
        const int am = am_s[tid];
        const unsigned long long below = (1ull << tid) - 1ull;
        int rank = 0, cl = 0, ch = 0;
        for (int e = 0; e < NEXP; ++e) {
            unsigned long long bal = __ballot(am == e);
            if (am == e) rank = (int)__popcll(bal & below);
            const int c = (int)__popcll(bal);
            if (tid == (e & 31)) { if (e < 32) cl = c; else ch = c; }
        }
        rank_g[row0 + tid] = rank;
        hist[blk * NEXP + tid]      = cl;
        hist[blk * NEXP + tid + 32] = ch;
    }
}

// ---------------------------------------------------------------------------
// K2: per-expert exclusive scan of 512 block histograms + me reduction +
// l_aux. Single block, 1024 threads: thread (g=tid>>6, e=tid&63) owns 32 blks.
// ---------------------------------------------------------------------------
__global__ __launch_bounds__(1024)
void scan_kernel(const int* __restrict__ hist,
                 int* __restrict__ offs,
                 const float* __restrict__ me_p,
                 float* __restrict__ out)
{
    __shared__ int   part[16][NEXP];
    __shared__ float pme2[16][NEXP];
    const int tid = threadIdx.x;
    const int e = tid & 63;
    const int g = tid >> 6;     // 0..15, 32 blocks each

    int ps = 0; float ms = 0.f;
    for (int i = 0; i < 32; ++i) {
        const int b = g * 32 + i;
        ps += hist[b * NEXP + e];
        ms += me_p[b * NEXP + e];
    }
    part[g][e] = ps;
    pme2[g][e] = ms;
    __syncthreads();

    if (tid < NEXP) {
        int run = 0; float me = 0.f;
        for (int gg = 0; gg < 16; ++gg) {
            const int v = part[gg][e];
            part[gg][e] = run;           // exclusive over groups
            run += v;
            me  += pme2[gg][e];
        }
        float la = me * (float)run;      // run == ce[e]
        #pragma unroll
        for (int o = 32; o > 0; o >>= 1)
            la += __shfl_down(la, o);
        if (tid == 0) {
            out[OFF_LAUX] = la * 2.384185791015625e-07f;  // 64 / 16384^2
            out[OFF_CAP]  = 256.0f;                        // ceil(N/E) * 1.0
            out[OFF_E]    = 64.0f;
        }
    }
    __syncthreads();

    int run2 = part[g][e];
    for (int i = 0; i < 32; ++i) {
        const int b = g * 32 + i;
        offs[b * NEXP + e] = run2;
        run2 += hist[b * NEXP + e];
    }
}

// ---------------------------------------------------------------------------
// K3: locations = in-block rank + scanned per-expert block offset
// ---------------------------------------------------------------------------
__global__ __launch_bounds__(256)
void loc_kernel(const int* __restrict__ idx_g,
                const int* __restrict__ rank_g,
                const int* __restrict__ offs,
                float* __restrict__ out)
{
    int t = blockIdx.x * 256 + threadIdx.x;
    int e = idx_g[t];
    int b = t >> 5;   // token / BM
    out[OFF_LOC + t] = (float)(rank_g[t] + offs[b * NEXP + e]);
}

extern "C" void kernel_launch(void* const* d_in, const int* in_sizes, int n_in,
                              void* d_out, int out_size, void* d_ws, size_t ws_size,
                              hipStream_t stream)
{
    const float* inp = (const float*)d_in[0];   // [16384, 2048]
    const float* wg  = (const float*)d_in[1];   // [64, 2048]
    float* out = (float*)d_out;

    // ws: w1a|w2a|w3a (3 x 256 KB bf16 frag arrays) | me_p 128KB | hist 128KB
    //     | offs 128KB | idx 64KB | rank 64KB  (~1.3 MB, fully rewritten/call)
    short8* w1a = (short8*)d_ws;
    short8* w2a = w1a + 16384;
    short8* w3a = w2a + 16384;
    float* me_p = (float*)(w3a + 16384);
    int* hist   = (int*)(me_p + NBLK * NEXP);
    int* offs   = hist + NBLK * NEXP;
    int* idx_g  = offs + NBLK * NEXP;
    int* rank_g = idx_g + N_TOK;

    hipLaunchKernelGGL(prep_w_kernel, dim3(64), dim3(256), 0, stream,
                       wg, w1a, w2a, w3a);
    hipLaunchKernelGGL(gate_mfma_kernel, dim3(NBLK), dim3(256), 0, stream,
                       inp, w1a, w2a, w3a, out, me_p, hist, idx_g, rank_g);
    hipLaunchKernelGGL(scan_kernel, dim3(1), dim3(1024), 0, stream,
                       hist, offs, me_p, out);
    hipLaunchKernelGGL(loc_kernel, dim3(N_TOK / 256), dim3(256), 0, stream,
                       idx_g, rank_g, offs, out);
}